// Round 1
// baseline (772.969 us; speedup 1.0000x reference)
//
#include <hip/hip_runtime.h>
#include <math.h>

#define BB 8
#define NN 256
#define DD 512
#define HH 16
#define KK 4
#define DKK 32
#define FFN_ 2048
#define NEGV -1e12f

// ---------------------------------------------------------------------------
// Generic tiled fp32 GEMM: C[M,N] = act(A[M,K] @ B[K,N] + bias[N])
// BM=BN=64, BK=16, 256 threads, 4x4 micro-tile per thread.
// ACT: 0 = none, 1 = silu, 2 = gelu (exact, erf-based)
// ---------------------------------------------------------------------------
template<int ACT>
__global__ __launch_bounds__(256) void gemm_kernel(
    const float* __restrict__ A, const float* __restrict__ Bm,
    const float* __restrict__ bias, float* __restrict__ C,
    int M, int N, int Kdim)
{
    __shared__ float As[16][68];  // stride 68: 4-float aligned, conflict-free
    __shared__ float Bs[16][64];

    const int t  = threadIdx.x;
    const int tx = t & 15, ty = t >> 4;
    const int n0 = blockIdx.x * 64, m0 = blockIdx.y * 64;

    const int am = t >> 2;          // 0..63 (A tile row)
    const int ak = (t & 3) * 4;     // 0,4,8,12 (A tile col quad)
    const int bk = t >> 4;          // 0..15 (B tile row)
    const int bn = (t & 15) * 4;    // 0..60 (B tile col quad)

    float acc[4][4] = {};

    for (int kt = 0; kt < Kdim; kt += 16) {
        float4 av = *(const float4*)(A + (size_t)(m0 + am) * Kdim + kt + ak);
        As[ak + 0][am] = av.x;
        As[ak + 1][am] = av.y;
        As[ak + 2][am] = av.z;
        As[ak + 3][am] = av.w;
        float4 bv = *(const float4*)(Bm + (size_t)(kt + bk) * N + n0 + bn);
        *(float4*)&Bs[bk][bn] = bv;
        __syncthreads();
        #pragma unroll
        for (int kk = 0; kk < 16; ++kk) {
            float4 a = *(const float4*)&As[kk][ty * 4];
            float4 b = *(const float4*)&Bs[kk][tx * 4];
            acc[0][0] += a.x * b.x; acc[0][1] += a.x * b.y;
            acc[0][2] += a.x * b.z; acc[0][3] += a.x * b.w;
            acc[1][0] += a.y * b.x; acc[1][1] += a.y * b.y;
            acc[1][2] += a.y * b.z; acc[1][3] += a.y * b.w;
            acc[2][0] += a.z * b.x; acc[2][1] += a.z * b.y;
            acc[2][2] += a.z * b.z; acc[2][3] += a.z * b.w;
            acc[3][0] += a.w * b.x; acc[3][1] += a.w * b.y;
            acc[3][2] += a.w * b.z; acc[3][3] += a.w * b.w;
        }
        __syncthreads();
    }

    #pragma unroll
    for (int i = 0; i < 4; ++i) {
        const int row = m0 + ty * 4 + i;
        #pragma unroll
        for (int j = 0; j < 4; ++j) {
            const int col = n0 + tx * 4 + j;
            float v = acc[i][j] + bias[col];
            if (ACT == 1) {                       // silu
                v = v / (1.0f + __expf(-v));
            } else if (ACT == 2) {                // gelu exact
                v = 0.5f * v * (1.0f + erff(v * 0.70710678118654752f));
            }
            C[(size_t)row * N + col] = v;
        }
    }
}

// ---------------------------------------------------------------------------
// Fused 4-scale masked attention. One block per (b, h, n); 256 threads.
// Computes s[m] = (q.k)*scale, then per scale: +bias, pad-mask, dist-mask,
// softmax; then one V pass accumulating all 4 scales; writes transposed
// msgT[b][m=(k*16+h)*32+d][n]  (== the scrambled W1 input matrix).
// ---------------------------------------------------------------------------
__global__ __launch_bounds__(256) void attn_kernel(
    const float* __restrict__ q, const float* __restrict__ k,
    const float* __restrict__ v, const float* __restrict__ attn_bias,
    const int* __restrict__ mask, const float* __restrict__ dist,
    const float* __restrict__ dist_bar, float* __restrict__ msgT)
{
    const int n = blockIdx.x, h = blockIdx.y, b = blockIdx.z;
    const int t = threadIdx.x;

    __shared__ float qs[DKK];
    __shared__ float w[KK][NN];
    __shared__ float red[NN];
    __shared__ float part[8][33];
    __shared__ float bar_s[KK];

    if (t < DKK) qs[t] = q[((size_t)(b * NN) + n) * DD + h * DKK + t];
    if (t < KK)  bar_s[t] = dist_bar[t];
    __syncthreads();

    // base score for column m = t
    const float4* k4 = (const float4*)(k + ((size_t)(b * NN) + t) * DD + h * DKK);
    const float4* q4 = (const float4*)qs;
    float dot = 0.0f;
    #pragma unroll
    for (int i = 0; i < 8; ++i) {
        float4 kv = k4[i], qv = q4[i];
        dot += kv.x * qv.x + kv.y * qv.y + kv.z * qv.z + kv.w * qv.w;
    }
    const float sbase = dot * 0.17677669529663687f;  // 1/sqrt(32)

    const int   mk = mask[((size_t)(b * NN) + n) * NN + t];
    const float nd = (n == 0 || t == 0) ? 0.0f
                     : dist[((size_t)(b * 255) + (n - 1)) * 255 + (t - 1)];

    for (int ks = 0; ks < KK; ++ks) {
        const float bias = attn_bias[(((size_t)(b * KK) + ks) * NN + n) * NN + t];
        const bool allowed = (n == 0) || (t == 0) || (nd < bar_s[ks]);
        const float s = (mk != 0 && allowed) ? (sbase + bias) : NEGV;

        red[t] = s; __syncthreads();
        for (int st = 128; st > 0; st >>= 1) {
            if (t < st) red[t] = fmaxf(red[t], red[t + st]);
            __syncthreads();
        }
        const float mx = red[0]; __syncthreads();

        const float e = __expf(s - mx);
        red[t] = e; __syncthreads();
        for (int st = 128; st > 0; st >>= 1) {
            if (t < st) red[t] += red[t + st];
            __syncthreads();
        }
        const float denom = red[0]; __syncthreads();

        w[ks][t] = e / denom;
    }
    __syncthreads();

    // V pass: thread t handles d = t&31, group grp = t>>5 covers 32 m-rows.
    const int d = t & 31, grp = t >> 5;
    float acc0 = 0, acc1 = 0, acc2 = 0, acc3 = 0;
    const float* vbase = v + ((size_t)(b * NN) + grp * 32) * DD + h * DKK + d;
    #pragma unroll 4
    for (int mm = 0; mm < 32; ++mm) {
        const float vv = vbase[(size_t)mm * DD];
        const int m = grp * 32 + mm;
        acc0 += w[0][m] * vv;
        acc1 += w[1][m] * vv;
        acc2 += w[2][m] * vv;
        acc3 += w[3][m] * vv;
    }

    #pragma unroll
    for (int ks = 0; ks < KK; ++ks) {
        const float a = (ks == 0) ? acc0 : (ks == 1) ? acc1 : (ks == 2) ? acc2 : acc3;
        part[grp][d] = a;
        __syncthreads();
        if (t < 32) {
            float s = 0.0f;
            #pragma unroll
            for (int g = 0; g < 8; ++g) s += part[g][t];
            // msgT flat: b*2048*256 + m*256 + n, m = (ks*16+h)*32 + t
            msgT[(size_t)b * (2048 * 256) + ((size_t)((ks * HH + h) * DKK + t)) * NN + n] = s;
        }
        __syncthreads();
    }
}

// ---------------------------------------------------------------------------
// Row-wise LayerNorm with residual: out = LN(a + r) * g + be. One block/row.
// ---------------------------------------------------------------------------
__global__ __launch_bounds__(256) void ln_kernel(
    const float* __restrict__ a, const float* __restrict__ r,
    const float* __restrict__ g, const float* __restrict__ be,
    float* __restrict__ out)
{
    const int row = blockIdx.x;
    const int t = threadIdx.x;
    __shared__ float red[256];

    const size_t base = (size_t)row * DD;
    const float z0 = a[base + t] + r[base + t];
    const float z1 = a[base + 256 + t] + r[base + 256 + t];

    red[t] = z0 + z1; __syncthreads();
    for (int s = 128; s > 0; s >>= 1) {
        if (t < s) red[t] += red[t + s];
        __syncthreads();
    }
    const float mean = red[0] * (1.0f / 512.0f); __syncthreads();

    const float d0 = z0 - mean, d1 = z1 - mean;
    red[t] = d0 * d0 + d1 * d1; __syncthreads();
    for (int s = 128; s > 0; s >>= 1) {
        if (t < s) red[t] += red[t + s];
        __syncthreads();
    }
    const float inv = rsqrtf(red[0] * (1.0f / 512.0f) + 1e-6f);

    out[base + t]       = d0 * inv * g[t]       + be[t];
    out[base + 256 + t] = d1 * inv * g[256 + t] + be[256 + t];
}

// ---------------------------------------------------------------------------
extern "C" void kernel_launch(void* const* d_in, const int* in_sizes, int n_in,
                              void* d_out, int out_size, void* d_ws, size_t ws_size,
                              hipStream_t stream)
{
    const float* x         = (const float*)d_in[0];
    const float* dist      = (const float*)d_in[1];
    const float* dist_bar  = (const float*)d_in[2];
    const float* attn_bias = (const float*)d_in[3];
    const int*   mask      = (const int*)d_in[4];
    // d_in[5] = num_heads (hardcoded 16)
    const float* Wq  = (const float*)d_in[6];  const float* bq  = (const float*)d_in[7];
    const float* Wk  = (const float*)d_in[8];  const float* bk  = (const float*)d_in[9];
    const float* Wv  = (const float*)d_in[10]; const float* bv  = (const float*)d_in[11];
    const float* W1  = (const float*)d_in[12]; const float* b1  = (const float*)d_in[13];
    const float* W2  = (const float*)d_in[14]; const float* b2  = (const float*)d_in[15];
    const float* g1  = (const float*)d_in[16]; const float* be1 = (const float*)d_in[17];
    const float* Wf1 = (const float*)d_in[18]; const float* bf1 = (const float*)d_in[19];
    const float* Wf2 = (const float*)d_in[20]; const float* bf2 = (const float*)d_in[21];
    const float* g2  = (const float*)d_in[22]; const float* be2 = (const float*)d_in[23];

    float* ws = (float*)d_ws;
    // workspace layout (floats); peak 8,388,608 floats = 32 MB
    float* qb   = ws + 0;          // [2048,512]   (reused as h1 after attn)
    float* kb   = ws + 1048576;    // [2048,512]   (reused as h2)
    float* vb   = ws + 2097152;    // [2048,512]   (reused as f)
    float* msgT = ws + 3145728;    // [8,2048,256] (reused as g3)
    float* yb   = ws + 7340032;    // [2048,512]   (live until the end)
    float* h1 = qb;
    float* h2 = kb;
    float* g3 = msgT;
    float* fb = vb;
    float* outp = (float*)d_out;

    dim3 thr(256);
    const int M = BB * NN;  // 2048

    // QKV projections: [2048,512] @ [512,512]
    gemm_kernel<0><<<dim3(DD / 64, M / 64), thr, 0, stream>>>(x, Wq, bq, qb, M, DD, DD);
    gemm_kernel<0><<<dim3(DD / 64, M / 64), thr, 0, stream>>>(x, Wk, bk, kb, M, DD, DD);
    gemm_kernel<0><<<dim3(DD / 64, M / 64), thr, 0, stream>>>(x, Wv, bv, vb, M, DD, DD);

    // fused 4-scale attention -> transposed msg (the scrambled W1 input)
    attn_kernel<<<dim3(NN, HH, BB), thr, 0, stream>>>(qb, kb, vb, attn_bias, mask,
                                                      dist, dist_bar, msgT);

    // h = silu(msgT @ W1 + b1) @ W2 + b2
    gemm_kernel<1><<<dim3(DD / 64, M / 64), thr, 0, stream>>>(msgT, W1, b1, h1, M, DD, 2048);
    gemm_kernel<0><<<dim3(DD / 64, M / 64), thr, 0, stream>>>(h1, W2, b2, h2, M, DD, DD);

    // y = LN(h + x)
    ln_kernel<<<dim3(M), thr, 0, stream>>>(h2, x, g1, be1, yb);

    // f = gelu(y @ Wf1 + bf1) @ Wf2 + bf2
    gemm_kernel<2><<<dim3(FFN_ / 64, M / 64), thr, 0, stream>>>(yb, Wf1, bf1, g3, M, FFN_, DD);
    gemm_kernel<0><<<dim3(DD / 64, M / 64), thr, 0, stream>>>(g3, Wf2, bf2, fb, M, DD, FFN_);

    // out = LN(f + y)
    ln_kernel<<<dim3(M), thr, 0, stream>>>(fb, yb, g2, be2, outp);
}

// Round 2
// 421.294 us; speedup vs baseline: 1.8348x; 1.8348x over previous
//
#include <hip/hip_runtime.h>
#include <math.h>

#define BB 8
#define NN 256
#define DD 512
#define HH 16
#define KK 4
#define DKK 32
#define FFN_ 2048
#define NEGV -1e12f

typedef __attribute__((ext_vector_type(8))) short bf16x8;
typedef __attribute__((ext_vector_type(4))) float f32x4;

__device__ __forceinline__ unsigned short f2bf(float f) {
    union { float f; unsigned int u; } v; v.f = f;
    unsigned int r = (v.u + 0x7FFFu + ((v.u >> 16) & 1u)) >> 16;
    return (unsigned short)r;
}

__device__ __forceinline__ void gload_lds16(const unsigned short* g, unsigned short* l) {
    __builtin_amdgcn_global_load_lds(
        (const __attribute__((address_space(1))) void*)g,
        (__attribute__((address_space(3))) void*)l, 16, 0, 0);
}

// ---------------------------------------------------------------------------
// Prep: transpose+convert 7 weight matrices W[K][N] fp32 -> Wt[N][K] bf16,
// and convert x fp32 -> bf16. One launch, blockIdx.z picks the task.
// ---------------------------------------------------------------------------
__global__ __launch_bounds__(256) void prep_kernel(
    const float* __restrict__ x,
    const float* __restrict__ Wq, const float* __restrict__ Wk,
    const float* __restrict__ Wv, const float* __restrict__ W1,
    const float* __restrict__ W2, const float* __restrict__ Wf1,
    const float* __restrict__ Wf2,
    unsigned short* __restrict__ xb,
    unsigned short* __restrict__ Wqt, unsigned short* __restrict__ Wkt,
    unsigned short* __restrict__ Wvt, unsigned short* __restrict__ W1t,
    unsigned short* __restrict__ W2t, unsigned short* __restrict__ Wf1t,
    unsigned short* __restrict__ Wf2t)
{
    const int z = blockIdx.z;
    const int t = threadIdx.x;

    if (z == 7) {  // x convert: 2048*512 = 1M elems, 1024 blocks * 256 thr * 4
        const int i0 = blockIdx.x * 1024 + t * 4;
        float4 xv = *(const float4*)(x + i0);
        ushort4 o;
        o.x = f2bf(xv.x); o.y = f2bf(xv.y); o.z = f2bf(xv.z); o.w = f2bf(xv.w);
        *(ushort4*)(xb + i0) = o;
        return;
    }

    const float* src; unsigned short* dst; int Kd, Nd;
    switch (z) {
        case 0: src = Wq;  dst = Wqt;  Kd = 512;  Nd = 512;  break;
        case 1: src = Wk;  dst = Wkt;  Kd = 512;  Nd = 512;  break;
        case 2: src = Wv;  dst = Wvt;  Kd = 512;  Nd = 512;  break;
        case 3: src = W1;  dst = W1t;  Kd = 2048; Nd = 512;  break;
        case 4: src = W2;  dst = W2t;  Kd = 512;  Nd = 512;  break;
        case 5: src = Wf1; dst = Wf1t; Kd = 512;  Nd = 2048; break;
        default: src = Wf2; dst = Wf2t; Kd = 2048; Nd = 512; break;
    }
    const int ktiles = Kd / 32, ntiles = Nd / 32;
    const int ti = blockIdx.x;
    if (ti >= ktiles * ntiles) return;
    const int k0 = (ti % ktiles) * 32, n0 = (ti / ktiles) * 32;

    __shared__ float tile[32][33];
    const int xx = t & 31, yy = t >> 5;  // 32 x 8
    #pragma unroll
    for (int r = 0; r < 4; ++r)
        tile[yy * 4 + r][xx] = src[(size_t)(k0 + yy * 4 + r) * Nd + n0 + xx];
    __syncthreads();
    #pragma unroll
    for (int r = 0; r < 4; ++r)
        dst[(size_t)(n0 + yy * 4 + r) * Kd + k0 + xx] = f2bf(tile[xx][yy * 4 + r]);
}

// ---------------------------------------------------------------------------
// bf16 MFMA GEMM: C[M,N] = act(A[M,K] @ Bt[N,K]^T + bias), fp32 accumulate.
// 64x64 tile, BK=64, 256 threads = 4 waves, wave w -> rows [w*16, w*16+16).
// A, Bt are bf16 (ushort). Staged via global_load_lds width=16.
// ACT: 0 none, 1 silu, 2 gelu. WF32/WBF16: which outputs to write.
// ---------------------------------------------------------------------------
template<int ACT, int WF32, int WBF16>
__global__ __launch_bounds__(256) void mfma_gemm(
    const unsigned short* __restrict__ A, const unsigned short* __restrict__ Bt,
    const float* __restrict__ bias, float* __restrict__ C,
    unsigned short* __restrict__ Cb, int M, int N, int Kdim)
{
    __shared__ unsigned short As[64 * 64];
    __shared__ unsigned short Bs[64 * 64];

    const int t = threadIdx.x;
    const int lane = t & 63, wv = t >> 6;
    const int n0 = blockIdx.x * 64, m0 = blockIdx.y * 64;

    const int r8 = lane >> 3;   // 0..7: row within 8-row staging chunk
    const int c8 = lane & 7;    // 0..7: 8-elem column chunk

    f32x4 acc[4];
    #pragma unroll
    for (int j = 0; j < 4; ++j) acc[j] = (f32x4){0.f, 0.f, 0.f, 0.f};

    const int mrow = lane & 15;     // fragment row/col within 16
    const int quad = lane >> 4;     // 0..3

    for (int kt = 0; kt < Kdim; kt += 64) {
        #pragma unroll
        for (int i = 0; i < 2; ++i) {
            const int rbase = wv * 16 + i * 8;
            gload_lds16(A  + (size_t)(m0 + rbase + r8) * Kdim + kt + c8 * 8,
                        As + rbase * 64);
            gload_lds16(Bt + (size_t)(n0 + rbase + r8) * Kdim + kt + c8 * 8,
                        Bs + rbase * 64);
        }
        __syncthreads();
        #pragma unroll
        for (int s = 0; s < 2; ++s) {
            const bf16x8 a = *(const bf16x8*)(As + (wv * 16 + mrow) * 64 + s * 32 + quad * 8);
            #pragma unroll
            for (int j = 0; j < 4; ++j) {
                const bf16x8 b = *(const bf16x8*)(Bs + (j * 16 + mrow) * 64 + s * 32 + quad * 8);
                acc[j] = __builtin_amdgcn_mfma_f32_16x16x32_bf16(a, b, acc[j], 0, 0, 0);
            }
        }
        __syncthreads();
    }

    // C/D layout: col = lane&15, row = (lane>>4)*4 + reg
    #pragma unroll
    for (int j = 0; j < 4; ++j) {
        const int col = n0 + j * 16 + mrow;
        const float bv = bias[col];
        #pragma unroll
        for (int r = 0; r < 4; ++r) {
            const int row = m0 + wv * 16 + quad * 4 + r;
            float v = acc[j][r] + bv;
            if (ACT == 1) v = v / (1.0f + __expf(-v));
            else if (ACT == 2) v = 0.5f * v * (1.0f + erff(v * 0.70710678118654752f));
            if (WF32)  C[(size_t)row * N + col] = v;
            if (WBF16) Cb[(size_t)row * N + col] = f2bf(v);
        }
    }
}

// ---------------------------------------------------------------------------
// Fused 4-scale masked attention, shuffle-reduction version.
// One block per (b,h,n); thread t = key column m. ~5 barriers total.
// Writes bf16 msgT[b][m=(ks*16+h)*32+d][n] (the scrambled W1-input layout).
// ---------------------------------------------------------------------------
__global__ __launch_bounds__(256) void attn_kernel(
    const float* __restrict__ q, const float* __restrict__ k,
    const float* __restrict__ v, const float* __restrict__ attn_bias,
    const int* __restrict__ mask, const float* __restrict__ dist,
    const float* __restrict__ dist_bar, unsigned short* __restrict__ msgT)
{
    const int n = blockIdx.x, h = blockIdx.y, b = blockIdx.z;
    const int t = threadIdx.x;
    const int lane = t & 63, wv = t >> 6;

    __shared__ float qs[DKK];
    __shared__ float w4[KK][NN];
    __shared__ float redm[4][KK];
    __shared__ float reds[4][KK];
    __shared__ float part[KK][8][33];

    if (t < DKK) qs[t] = q[((size_t)(b * NN) + n) * DD + h * DKK + t];
    __syncthreads();

    // base score for key column m = t
    const float4* k4 = (const float4*)(k + ((size_t)(b * NN) + t) * DD + h * DKK);
    const float4* q4 = (const float4*)qs;
    float dot = 0.0f;
    #pragma unroll
    for (int i = 0; i < 8; ++i) {
        float4 kv = k4[i], qv = q4[i];
        dot += kv.x * qv.x + kv.y * qv.y + kv.z * qv.z + kv.w * qv.w;
    }
    const float sbase = dot * 0.17677669529663687f;  // 1/sqrt(32)

    const int   mk = mask[((size_t)(b * NN) + n) * NN + t];
    const float nd = (n == 0 || t == 0) ? 0.0f
                     : dist[((size_t)(b * 255) + (n - 1)) * 255 + (t - 1)];

    float s[KK];
    #pragma unroll
    for (int ks = 0; ks < KK; ++ks) {
        const float bias = attn_bias[(((size_t)(b * KK) + ks) * NN + n) * NN + t];
        const bool allowed = (n == 0) || (t == 0) || (nd < dist_bar[ks]);
        s[ks] = (mk != 0 && allowed) ? (sbase + bias) : NEGV;
    }

    // joint 4-scale max: wave butterfly, then cross-wave combine via LDS
    float m0 = s[0], m1 = s[1], m2 = s[2], m3 = s[3];
    #pragma unroll
    for (int off = 32; off > 0; off >>= 1) {
        m0 = fmaxf(m0, __shfl_xor(m0, off));
        m1 = fmaxf(m1, __shfl_xor(m1, off));
        m2 = fmaxf(m2, __shfl_xor(m2, off));
        m3 = fmaxf(m3, __shfl_xor(m3, off));
    }
    if (lane == 0) { redm[wv][0] = m0; redm[wv][1] = m1; redm[wv][2] = m2; redm[wv][3] = m3; }
    __syncthreads();
    const float M0 = fmaxf(fmaxf(redm[0][0], redm[1][0]), fmaxf(redm[2][0], redm[3][0]));
    const float M1 = fmaxf(fmaxf(redm[0][1], redm[1][1]), fmaxf(redm[2][1], redm[3][1]));
    const float M2 = fmaxf(fmaxf(redm[0][2], redm[1][2]), fmaxf(redm[2][2], redm[3][2]));
    const float M3 = fmaxf(fmaxf(redm[0][3], redm[1][3]), fmaxf(redm[2][3], redm[3][3]));

    float e0 = __expf(s[0] - M0), e1 = __expf(s[1] - M1);
    float e2 = __expf(s[2] - M2), e3 = __expf(s[3] - M3);
    float t0 = e0, t1 = e1, t2 = e2, t3 = e3;
    #pragma unroll
    for (int off = 32; off > 0; off >>= 1) {
        t0 += __shfl_xor(t0, off);
        t1 += __shfl_xor(t1, off);
        t2 += __shfl_xor(t2, off);
        t3 += __shfl_xor(t3, off);
    }
    if (lane == 0) { reds[wv][0] = t0; reds[wv][1] = t1; reds[wv][2] = t2; reds[wv][3] = t3; }
    __syncthreads();
    const float S0 = reds[0][0] + reds[1][0] + reds[2][0] + reds[3][0];
    const float S1 = reds[0][1] + reds[1][1] + reds[2][1] + reds[3][1];
    const float S2 = reds[0][2] + reds[1][2] + reds[2][2] + reds[3][2];
    const float S3 = reds[0][3] + reds[1][3] + reds[2][3] + reds[3][3];

    w4[0][t] = e0 * (1.0f / S0);
    w4[1][t] = e1 * (1.0f / S1);
    w4[2][t] = e2 * (1.0f / S2);
    w4[3][t] = e3 * (1.0f / S3);
    __syncthreads();

    // V pass: thread t -> d = t&31, group grp = t>>5 covers m in [grp*32, grp*32+32)
    const int d = t & 31, grp = t >> 5;
    float a0 = 0, a1 = 0, a2 = 0, a3 = 0;
    const float* vbase = v + ((size_t)(b * NN) + grp * 32) * DD + h * DKK + d;
    #pragma unroll 4
    for (int mm = 0; mm < 32; ++mm) {
        const float vv = vbase[(size_t)mm * DD];
        const int m = grp * 32 + mm;
        a0 += w4[0][m] * vv;
        a1 += w4[1][m] * vv;
        a2 += w4[2][m] * vv;
        a3 += w4[3][m] * vv;
    }
    part[0][grp][d] = a0;
    part[1][grp][d] = a1;
    part[2][grp][d] = a2;
    part[3][grp][d] = a3;
    __syncthreads();

    if (t < 128) {
        const int ks = t >> 5, dd = t & 31;
        float sum = 0.0f;
        #pragma unroll
        for (int g = 0; g < 8; ++g) sum += part[ks][g][dd];
        msgT[(size_t)b * (2048 * 256) + ((size_t)((ks * HH + h) * DKK + dd)) * NN + n] = f2bf(sum);
    }
}

// ---------------------------------------------------------------------------
// Row LayerNorm with residual: out = LN(a + r) * g + be (+ optional bf16 copy)
// ---------------------------------------------------------------------------
__global__ __launch_bounds__(256) void ln_kernel(
    const float* __restrict__ a, const float* __restrict__ r,
    const float* __restrict__ g, const float* __restrict__ be,
    float* __restrict__ out, unsigned short* __restrict__ outb)
{
    const int row = blockIdx.x;
    const int t = threadIdx.x;
    __shared__ float red[256];

    const size_t base = (size_t)row * DD;
    const float z0 = a[base + t] + r[base + t];
    const float z1 = a[base + 256 + t] + r[base + 256 + t];

    red[t] = z0 + z1; __syncthreads();
    for (int s = 128; s > 0; s >>= 1) {
        if (t < s) red[t] += red[t + s];
        __syncthreads();
    }
    const float mean = red[0] * (1.0f / 512.0f); __syncthreads();

    const float d0 = z0 - mean, d1 = z1 - mean;
    red[t] = d0 * d0 + d1 * d1; __syncthreads();
    for (int s = 128; s > 0; s >>= 1) {
        if (t < s) red[t] += red[t + s];
        __syncthreads();
    }
    const float inv = rsqrtf(red[0] * (1.0f / 512.0f) + 1e-6f);

    const float o0 = d0 * inv * g[t] + be[t];
    const float o1 = d1 * inv * g[256 + t] + be[256 + t];
    out[base + t] = o0;
    out[base + 256 + t] = o1;
    if (outb) {
        outb[base + t] = f2bf(o0);
        outb[base + 256 + t] = f2bf(o1);
    }
}

// ---------------------------------------------------------------------------
extern "C" void kernel_launch(void* const* d_in, const int* in_sizes, int n_in,
                              void* d_out, int out_size, void* d_ws, size_t ws_size,
                              hipStream_t stream)
{
    const float* x         = (const float*)d_in[0];
    const float* dist      = (const float*)d_in[1];
    const float* dist_bar  = (const float*)d_in[2];
    const float* attn_bias = (const float*)d_in[3];
    const int*   mask      = (const int*)d_in[4];
    const float* Wq  = (const float*)d_in[6];  const float* bq  = (const float*)d_in[7];
    const float* Wk  = (const float*)d_in[8];  const float* bk  = (const float*)d_in[9];
    const float* Wv  = (const float*)d_in[10]; const float* bv  = (const float*)d_in[11];
    const float* W1  = (const float*)d_in[12]; const float* b1  = (const float*)d_in[13];
    const float* W2  = (const float*)d_in[14]; const float* b2  = (const float*)d_in[15];
    const float* g1  = (const float*)d_in[16]; const float* be1 = (const float*)d_in[17];
    const float* Wf1 = (const float*)d_in[18]; const float* bf1 = (const float*)d_in[19];
    const float* Wf2 = (const float*)d_in[20]; const float* bf2 = (const float*)d_in[21];
    const float* g2  = (const float*)d_in[22]; const float* be2 = (const float*)d_in[23];

    float* ws = (float*)d_ws;
    // ----- workspace layout (float units), peak 7,864,320 floats = 30 MB -----
    float*          qb    = ws + 0;        // [2048,512] f32 -> h1(bf16) -> f(f32)
    float*          kb    = ws + 1048576;  // [2048,512] f32 -> h2(f32)
    float*          vb    = ws + 2097152;  // [2048,512] f32 -> y(f32)
    unsigned short* msgT  = (unsigned short*)(ws + 3145728); // [8*2048*256] bf16 -> g3(bf16)
    unsigned short* xb    = (unsigned short*)(ws + 5242880); // [2048*512] bf16 -> yb16
    unsigned short* Wqt   = (unsigned short*)(ws + 5767168);
    unsigned short* Wkt   = (unsigned short*)(ws + 5898240);
    unsigned short* Wvt   = (unsigned short*)(ws + 6029312);
    unsigned short* W2t   = (unsigned short*)(ws + 6160384);
    unsigned short* W1t   = (unsigned short*)(ws + 6291456);
    unsigned short* Wf1t  = (unsigned short*)(ws + 6815744);
    unsigned short* Wf2t  = (unsigned short*)(ws + 7340032);

    unsigned short* h1   = (unsigned short*)qb;    // [2048,512] bf16
    float*          h2   = kb;                     // [2048,512] f32
    float*          yb   = vb;                     // [2048,512] f32
    unsigned short* yb16 = xb;                     // [2048,512] bf16
    unsigned short* g3   = msgT;                   // [2048,2048] bf16
    float*          fb   = qb;                     // [2048,512] f32
    float*          outp = (float*)d_out;

    dim3 thr(256);
    const int M = BB * NN;  // 2048

    // prep: weight transposes (bf16) + x convert
    prep_kernel<<<dim3(1024, 1, 8), thr, 0, stream>>>(
        x, Wq, Wk, Wv, W1, W2, Wf1, Wf2, xb, Wqt, Wkt, Wvt, W1t, W2t, Wf1t, Wf2t);

    // QKV projections (bf16 MFMA, fp32 out)
    mfma_gemm<0,1,0><<<dim3(DD/64, M/64), thr, 0, stream>>>(xb, Wqt, bq, qb, nullptr, M, DD, DD);
    mfma_gemm<0,1,0><<<dim3(DD/64, M/64), thr, 0, stream>>>(xb, Wkt, bk, kb, nullptr, M, DD, DD);
    mfma_gemm<0,1,0><<<dim3(DD/64, M/64), thr, 0, stream>>>(xb, Wvt, bv, vb, nullptr, M, DD, DD);

    // fused 4-scale attention -> bf16 msgT (scrambled W1-input layout)
    attn_kernel<<<dim3(NN, HH, BB), thr, 0, stream>>>(qb, kb, vb, attn_bias, mask,
                                                      dist, dist_bar, msgT);

    // h = silu(msgT @ W1 + b1) @ W2 + b2
    mfma_gemm<1,0,1><<<dim3(DD/64, M/64), thr, 0, stream>>>(msgT, W1t, b1, nullptr, h1, M, DD, 2048);
    mfma_gemm<0,1,0><<<dim3(DD/64, M/64), thr, 0, stream>>>(h1, W2t, b2, h2, nullptr, M, DD, DD);

    // y = LN(h + x)  (fp32 + bf16 copy for the Wf1 GEMM)
    ln_kernel<<<dim3(M), thr, 0, stream>>>(h2, x, g1, be1, yb, yb16);

    // f = gelu(y @ Wf1 + bf1) @ Wf2 + bf2
    mfma_gemm<2,0,1><<<dim3(FFN_/64, M/64), thr, 0, stream>>>(yb16, Wf1t, bf1, nullptr, g3, M, FFN_, DD);
    mfma_gemm<0,1,0><<<dim3(DD/64, M/64), thr, 0, stream>>>(g3, Wf2t, bf2, fb, nullptr, M, DD, FFN_);

    // out = LN(f + y)
    ln_kernel<<<dim3(M), thr, 0, stream>>>(fb, yb, g2, be2, outp, nullptr);
}

// Round 3
// 267.024 us; speedup vs baseline: 2.8948x; 1.5777x over previous
//
#include <hip/hip_runtime.h>
#include <math.h>

#define BB 8
#define NN 256
#define DD 512
#define HH 16
#define KK 4
#define DKK 32
#define FFN_ 2048
#define NEGV -1e12f

typedef __attribute__((ext_vector_type(8))) short bf16x8;
typedef __attribute__((ext_vector_type(4))) float f32x4;

__device__ __forceinline__ unsigned short f2bf(float f) {
    union { float f; unsigned int u; } v; v.f = f;
    unsigned int r = (v.u + 0x7FFFu + ((v.u >> 16) & 1u)) >> 16;
    return (unsigned short)r;
}
__device__ __forceinline__ float bf2f(unsigned short u) {
    union { unsigned int i; float f; } v; v.i = ((unsigned int)u) << 16;
    return v.f;
}
__device__ __forceinline__ void gload_lds16(const unsigned short* g, unsigned short* l) {
    __builtin_amdgcn_global_load_lds(
        (const __attribute__((address_space(1))) void*)g,
        (__attribute__((address_space(3))) void*)l, 16, 0, 0);
}

// ---------------------------------------------------------------------------
// Prep: weight transposes fp32->bf16 (Wt[N][K]), x->bf16, bias concat.
// ---------------------------------------------------------------------------
__global__ __launch_bounds__(256) void prep_kernel(
    const float* __restrict__ x,
    const float* __restrict__ Wq, const float* __restrict__ Wk,
    const float* __restrict__ Wv, const float* __restrict__ W1,
    const float* __restrict__ W2, const float* __restrict__ Wf1,
    const float* __restrict__ Wf2,
    const float* __restrict__ bq, const float* __restrict__ bk,
    const float* __restrict__ bv,
    unsigned short* __restrict__ xb, unsigned short* __restrict__ Wqkvt,
    unsigned short* __restrict__ W1t, unsigned short* __restrict__ W2t,
    unsigned short* __restrict__ Wf1t, unsigned short* __restrict__ Wf2t,
    float* __restrict__ bqkv)
{
    const int z = blockIdx.z;
    const int t = threadIdx.x;

    if (z == 7) {  // x convert
        const int i0 = blockIdx.x * 1024 + t * 4;
        float4 xv = *(const float4*)(x + i0);
        ushort4 o;
        o.x = f2bf(xv.x); o.y = f2bf(xv.y); o.z = f2bf(xv.z); o.w = f2bf(xv.w);
        *(ushort4*)(xb + i0) = o;
        return;
    }
    if (z == 8) {  // bias concat (6 blocks)
        if (blockIdx.x >= 6) return;
        const int i = blockIdx.x * 256 + t;
        float v = (i < 512) ? bq[i] : (i < 1024) ? bk[i - 512] : bv[i - 1024];
        bqkv[i] = v;
        return;
    }

    const float* src; unsigned short* dst; int Kd, Nd;
    switch (z) {
        case 0: src = Wq;  dst = Wqkvt;              Kd = 512;  Nd = 512;  break;
        case 1: src = Wk;  dst = Wqkvt + 512 * 512;  Kd = 512;  Nd = 512;  break;
        case 2: src = Wv;  dst = Wqkvt + 1024 * 512; Kd = 512;  Nd = 512;  break;
        case 3: src = W1;  dst = W1t;  Kd = 2048; Nd = 512;  break;
        case 4: src = W2;  dst = W2t;  Kd = 512;  Nd = 512;  break;
        case 5: src = Wf1; dst = Wf1t; Kd = 512;  Nd = 2048; break;
        default: src = Wf2; dst = Wf2t; Kd = 2048; Nd = 512; break;
    }
    const int ktiles = Kd / 32, ntiles = Nd / 32;
    const int ti = blockIdx.x;
    if (ti >= ktiles * ntiles) return;
    const int k0 = (ti % ktiles) * 32, n0 = (ti / ktiles) * 32;

    __shared__ float tile[32][33];
    const int xx = t & 31, yy = t >> 5;
    #pragma unroll
    for (int r = 0; r < 4; ++r)
        tile[yy * 4 + r][xx] = src[(size_t)(k0 + yy * 4 + r) * Nd + n0 + xx];
    __syncthreads();
    #pragma unroll
    for (int r = 0; r < 4; ++r)
        dst[(size_t)(n0 + yy * 4 + r) * Kd + k0 + xx] = f2bf(tile[xx][yy * 4 + r]);
}

// ---------------------------------------------------------------------------
// Prep combined mask+bias (h-independent): biasMs[(b*4+ks)*64+rg][m][i],
// i = n&3, rg = n>>2, bf16.  val = (mask && allowed) ? bias : NEG.
// One block per (b,ks,rg): reads 4 bias rows, writes 2 KB contiguous.
// ---------------------------------------------------------------------------
__global__ __launch_bounds__(256) void prep_bias(
    const float* __restrict__ attn_bias, const int* __restrict__ mask,
    const float* __restrict__ dist, const float* __restrict__ dist_bar,
    unsigned short* __restrict__ biasMs)
{
    const int bx = blockIdx.x;            // ((b*4+ks)*64 + rg)
    const int rg = bx & 63, ks = (bx >> 6) & 3, b = bx >> 8;
    const int m = threadIdx.x;
    const float bar = dist_bar[ks];

    ushort4 o;
    unsigned short* po = (unsigned short*)&o;
    #pragma unroll
    for (int i = 0; i < 4; ++i) {
        const int n = rg * 4 + i;
        const int mk = mask[((size_t)(b * NN) + n) * NN + m];
        bool allowed = (n == 0) || (m == 0);
        if (!allowed)
            allowed = dist[((size_t)(b * 255) + (n - 1)) * 255 + (m - 1)] < bar;
        const float bias = attn_bias[(((size_t)(b * KK) + ks) * NN + n) * NN + m];
        po[i] = f2bf((mk != 0 && allowed) ? bias : NEGV);
    }
    *(ushort4*)(biasMs + (size_t)bx * 1024 + m * 4) = o;
}

// ---------------------------------------------------------------------------
// 128x128 MFMA GEMM (m97-style): C = act(A[M,K] @ Bt[N,K]^T + bias), bf16 in,
// fp32 acc.  BK=64, 256 thr = 4 waves (2x2), 32 MFMA per staging barrier.
// EPI 0: bf16 store pitch N.  EPI 1: QKV split (col<1024 -> Cb, else vT^T).
// ---------------------------------------------------------------------------
template<int ACT, int EPI>
__global__ __launch_bounds__(256) void mfma_gemm128(
    const unsigned short* __restrict__ A, const unsigned short* __restrict__ Bt,
    const float* __restrict__ bias, unsigned short* __restrict__ Cb,
    unsigned short* __restrict__ vT, int M, int N, int Kdim)
{
    __shared__ unsigned short As[128 * 64];
    __shared__ unsigned short Bs[128 * 64];

    const int t = threadIdx.x, lane = t & 63, wv = t >> 6;
    const int n0 = blockIdx.x * 128, m0 = blockIdx.y * 128;
    const int wm = wv >> 1, wn = wv & 1;
    const int L = lane & 15, qd = lane >> 4;
    const int sr = lane >> 3, sc = lane & 7;   // staging: 8 rows x 8 chunks

    f32x4 acc[4][4];
    #pragma unroll
    for (int i = 0; i < 4; ++i)
        #pragma unroll
        for (int j = 0; j < 4; ++j) acc[i][j] = (f32x4){0.f, 0.f, 0.f, 0.f};

    for (int kt = 0; kt < Kdim; kt += 64) {
        #pragma unroll
        for (int p = 0; p < 4; ++p) {
            const int rbase = wv * 32 + p * 8;
            gload_lds16(A  + (size_t)(m0 + rbase + sr) * Kdim + kt + sc * 8,
                        As + rbase * 64);
            gload_lds16(Bt + (size_t)(n0 + rbase + sr) * Kdim + kt + sc * 8,
                        Bs + rbase * 64);
        }
        __syncthreads();
        #pragma unroll
        for (int s = 0; s < 2; ++s) {
            bf16x8 af[4], bf[4];
            #pragma unroll
            for (int i = 0; i < 4; ++i)
                af[i] = *(const bf16x8*)(As + (wm * 64 + i * 16 + L) * 64 + s * 32 + qd * 8);
            #pragma unroll
            for (int j = 0; j < 4; ++j)
                bf[j] = *(const bf16x8*)(Bs + (wn * 64 + j * 16 + L) * 64 + s * 32 + qd * 8);
            #pragma unroll
            for (int i = 0; i < 4; ++i)
                #pragma unroll
                for (int j = 0; j < 4; ++j)
                    acc[i][j] = __builtin_amdgcn_mfma_f32_16x16x32_bf16(af[i], bf[j], acc[i][j], 0, 0, 0);
        }
        __syncthreads();
    }

    #pragma unroll
    for (int j = 0; j < 4; ++j) {
        const int col = n0 + wn * 64 + j * 16 + L;
        const float bv = bias[col];
        #pragma unroll
        for (int i = 0; i < 4; ++i) {
            const int rowb = m0 + wm * 64 + i * 16 + qd * 4;
            if (EPI == 1 && col >= 1024) {
                ushort4 pk;
                unsigned short* pp = (unsigned short*)&pk;
                #pragma unroll
                for (int r = 0; r < 4; ++r) pp[r] = f2bf(acc[i][j][r] + bv);
                *(ushort4*)(vT + (size_t)(col - 1024) * 2048 + rowb) = pk;
            } else {
                #pragma unroll
                for (int r = 0; r < 4; ++r) {
                    float v = acc[i][j][r] + bv;
                    if (ACT == 1) v = v / (1.0f + __expf(-v));
                    else if (ACT == 2) v = 0.5f * v * (1.0f + erff(v * 0.70710678118654752f));
                    Cb[(size_t)(rowb + r) * N + col] = f2bf(v);
                }
            }
        }
    }
}

// ---------------------------------------------------------------------------
// 64x64 MFMA GEMM (R2-proven), bf16 out only.
// ---------------------------------------------------------------------------
template<int ACT>
__global__ __launch_bounds__(256) void mfma_gemm64(
    const unsigned short* __restrict__ A, const unsigned short* __restrict__ Bt,
    const float* __restrict__ bias, unsigned short* __restrict__ Cb,
    int M, int N, int Kdim)
{
    __shared__ unsigned short As[64 * 64];
    __shared__ unsigned short Bs[64 * 64];

    const int t = threadIdx.x, lane = t & 63, wv = t >> 6;
    const int n0 = blockIdx.x * 64, m0 = blockIdx.y * 64;
    const int r8 = lane >> 3, c8 = lane & 7;
    const int L = lane & 15, qd = lane >> 4;

    f32x4 acc[4];
    #pragma unroll
    for (int j = 0; j < 4; ++j) acc[j] = (f32x4){0.f, 0.f, 0.f, 0.f};

    for (int kt = 0; kt < Kdim; kt += 64) {
        #pragma unroll
        for (int i = 0; i < 2; ++i) {
            const int rbase = wv * 16 + i * 8;
            gload_lds16(A  + (size_t)(m0 + rbase + r8) * Kdim + kt + c8 * 8, As + rbase * 64);
            gload_lds16(Bt + (size_t)(n0 + rbase + r8) * Kdim + kt + c8 * 8, Bs + rbase * 64);
        }
        __syncthreads();
        #pragma unroll
        for (int s = 0; s < 2; ++s) {
            const bf16x8 a = *(const bf16x8*)(As + (wv * 16 + L) * 64 + s * 32 + qd * 8);
            #pragma unroll
            for (int j = 0; j < 4; ++j) {
                const bf16x8 b = *(const bf16x8*)(Bs + (j * 16 + L) * 64 + s * 32 + qd * 8);
                acc[j] = __builtin_amdgcn_mfma_f32_16x16x32_bf16(a, b, acc[j], 0, 0, 0);
            }
        }
        __syncthreads();
    }

    #pragma unroll
    for (int j = 0; j < 4; ++j) {
        const int col = n0 + j * 16 + L;
        const float bv = bias[col];
        #pragma unroll
        for (int r = 0; r < 4; ++r) {
            const int row = m0 + wv * 16 + qd * 4 + r;
            float v = acc[j][r] + bv;
            if (ACT == 1) v = v / (1.0f + __expf(-v));
            else if (ACT == 2) v = 0.5f * v * (1.0f + erff(v * 0.70710678118654752f));
            Cb[(size_t)row * N + col] = f2bf(v);
        }
    }
}

// ---------------------------------------------------------------------------
// MFMA attention: one block per (b, h, 64-query tile).  QK^T and PV on MFMA,
// softmax in C-layout registers (quad shuffles), P unnormalized in LDS
// (wave-private), normalization folded into O epilogue.  Coalesced msgT.
// ---------------------------------------------------------------------------
__global__ __launch_bounds__(256) void attn_kernel(
    const unsigned short* __restrict__ qkvb, const unsigned short* __restrict__ vT,
    const unsigned short* __restrict__ biasMs, unsigned short* __restrict__ msgT)
{
    const int qt = blockIdx.x, h = blockIdx.y, b = blockIdx.z;
    const int q0 = qt * 64;
    const int t = threadIdx.x, lane = t & 63, wv = t >> 6;
    const int L = lane & 15, qd = lane >> 4;

    __shared__ unsigned short Qs[64 * 32];
    __shared__ unsigned short Ks[256 * 32];
    __shared__ unsigned short Vs[32 * 264];
    __shared__ unsigned short Ps[64 * 264];
    __shared__ unsigned short Ot[32 * 72];

    // ---- stage Q (1 instr/wave) and K (4 instr/wave), contiguous pitch 32
    {
        const int r = lane >> 2, c = lane & 3;
        gload_lds16(qkvb + (size_t)(b * NN + q0 + wv * 16 + r) * 1536 + h * DKK + c * 8,
                    Qs + wv * 16 * 32);
        #pragma unroll
        for (int p = 0; p < 4; ++p)
            gload_lds16(qkvb + (size_t)(b * NN + p * 64 + wv * 16 + r) * 1536 + 512 + h * DKK + c * 8,
                        Ks + (p * 64 + wv * 16) * 32);
    }
    // ---- stage V^T [32 d][256 m] with pitch 264 (manual, padded)
    {
        const int vr = t >> 3, seg = t & 7;
        const unsigned short* gv = vT + (size_t)(h * DKK + vr) * 2048 + b * NN + seg * 32;
        #pragma unroll
        for (int i = 0; i < 4; ++i) {
            bf16x8 vv = *(const bf16x8*)(gv + i * 8);
            *(bf16x8*)(Vs + vr * 264 + seg * 32 + i * 8) = vv;
        }
    }
    __syncthreads();

    // ---- QK^T: S[j] = 16x16 tile, keys j*16..j*16+16
    f32x4 S[16];
    #pragma unroll
    for (int j = 0; j < 16; ++j) S[j] = (f32x4){0.f, 0.f, 0.f, 0.f};
    {
        const bf16x8 aq = *(const bf16x8*)(Qs + (wv * 16 + L) * 32 + qd * 8);
        #pragma unroll
        for (int j = 0; j < 16; ++j) {
            const bf16x8 bk = *(const bf16x8*)(Ks + (j * 16 + L) * 32 + qd * 8);
            S[j] = __builtin_amdgcn_mfma_f32_16x16x32_bf16(aq, bk, S[j], 0, 0, 0);
        }
    }
    const float scale = 0.17677669529663687f;  // 1/sqrt(32)
    const int rgb = (q0 + wv * 16) >> 2;       // rowgroup base, + qd

    for (int ks = 0; ks < KK; ++ks) {
        const unsigned short* bp = biasMs + ((size_t)((b * KK + ks) * 64 + rgb + qd)) * 1024;

        // pass 1: row max (rows = qd*4 + r, in C layout)
        ushort4 b4[16];
        float mx[4] = {-3e38f, -3e38f, -3e38f, -3e38f};
        #pragma unroll
        for (int j = 0; j < 16; ++j) {
            b4[j] = *(const ushort4*)(bp + (j * 16 + L) * 4);
            const unsigned short* pb = (const unsigned short*)&b4[j];
            #pragma unroll
            for (int r = 0; r < 4; ++r)
                mx[r] = fmaxf(mx[r], S[j][r] * scale + bf2f(pb[r]));
        }
        #pragma unroll
        for (int off = 8; off > 0; off >>= 1)
            #pragma unroll
            for (int r = 0; r < 4; ++r)
                mx[r] = fmaxf(mx[r], __shfl_xor(mx[r], off));

        // pass 2: exp, sum, write unnormalized P (wave-private rows)
        float sm[4] = {0.f, 0.f, 0.f, 0.f};
        #pragma unroll
        for (int j = 0; j < 16; ++j) {
            const unsigned short* pb = (const unsigned short*)&b4[j];
            #pragma unroll
            for (int r = 0; r < 4; ++r) {
                const float e = __expf(S[j][r] * scale + bf2f(pb[r]) - mx[r]);
                sm[r] += e;
                Ps[(wv * 16 + qd * 4 + r) * 264 + j * 16 + L] = f2bf(e);
            }
        }
        #pragma unroll
        for (int off = 8; off > 0; off >>= 1)
            #pragma unroll
            for (int r = 0; r < 4; ++r)
                sm[r] += __shfl_xor(sm[r], off);
        float inv[4];
        #pragma unroll
        for (int r = 0; r < 4; ++r) inv[r] = 1.0f / sm[r];

        // PV: O[jt] = P(16 rows) x V^T, normalize in epilogue
        f32x4 O[2];
        O[0] = (f32x4){0.f, 0.f, 0.f, 0.f};
        O[1] = (f32x4){0.f, 0.f, 0.f, 0.f};
        #pragma unroll
        for (int kc = 0; kc < 8; ++kc) {
            const bf16x8 ap = *(const bf16x8*)(Ps + (wv * 16 + L) * 264 + kc * 32 + qd * 8);
            #pragma unroll
            for (int jt = 0; jt < 2; ++jt) {
                const bf16x8 bv = *(const bf16x8*)(Vs + (jt * 16 + L) * 264 + kc * 32 + qd * 8);
                O[jt] = __builtin_amdgcn_mfma_f32_16x16x32_bf16(ap, bv, O[jt], 0, 0, 0);
            }
        }
        #pragma unroll
        for (int jt = 0; jt < 2; ++jt)
            #pragma unroll
            for (int r = 0; r < 4; ++r)
                Ot[(jt * 16 + L) * 72 + wv * 16 + qd * 4 + r] = f2bf(O[jt][r] * inv[r]);
        __syncthreads();   // Ot complete

        // coalesced store: thread t -> d = t>>3, 8-elem chunk c = t&7
        {
            const int dd = t >> 3, cc = t & 7;
            bf16x8 ov = *(const bf16x8*)(Ot + dd * 72 + cc * 8);
            *(bf16x8*)(msgT + (size_t)b * 524288 +
                       ((size_t)((ks * HH + h) * DKK + dd)) * NN + q0 + cc * 8) = ov;
        }
        __syncthreads();   // Ot reads done before next scale overwrites
    }
}

// ---------------------------------------------------------------------------
// Row LayerNorm with residual: out = LN(bf16 a + f32 r) * g + be (+ bf16 copy)
// ---------------------------------------------------------------------------
__global__ __launch_bounds__(256) void ln_kernel(
    const unsigned short* __restrict__ a, const float* __restrict__ r,
    const float* __restrict__ g, const float* __restrict__ be,
    float* __restrict__ out, unsigned short* __restrict__ outb)
{
    const int row = blockIdx.x;
    const int t = threadIdx.x;
    __shared__ float red[256];

    const size_t base = (size_t)row * DD;
    const float z0 = bf2f(a[base + t]) + r[base + t];
    const float z1 = bf2f(a[base + 256 + t]) + r[base + 256 + t];

    red[t] = z0 + z1; __syncthreads();
    for (int s = 128; s > 0; s >>= 1) {
        if (t < s) red[t] += red[t + s];
        __syncthreads();
    }
    const float mean = red[0] * (1.0f / 512.0f); __syncthreads();

    const float d0 = z0 - mean, d1 = z1 - mean;
    red[t] = d0 * d0 + d1 * d1; __syncthreads();
    for (int s = 128; s > 0; s >>= 1) {
        if (t < s) red[t] += red[t + s];
        __syncthreads();
    }
    const float inv = rsqrtf(red[0] * (1.0f / 512.0f) + 1e-6f);

    const float o0 = d0 * inv * g[t] + be[t];
    const float o1 = d1 * inv * g[256 + t] + be[256 + t];
    out[base + t] = o0;
    out[base + 256 + t] = o1;
    if (outb) {
        outb[base + t] = f2bf(o0);
        outb[base + 256 + t] = f2bf(o1);
    }
}

// ---------------------------------------------------------------------------
extern "C" void kernel_launch(void* const* d_in, const int* in_sizes, int n_in,
                              void* d_out, int out_size, void* d_ws, size_t ws_size,
                              hipStream_t stream)
{
    const float* x         = (const float*)d_in[0];
    const float* dist      = (const float*)d_in[1];
    const float* dist_bar  = (const float*)d_in[2];
    const float* attn_bias = (const float*)d_in[3];
    const int*   mask      = (const int*)d_in[4];
    const float* Wq  = (const float*)d_in[6];  const float* bq  = (const float*)d_in[7];
    const float* Wk  = (const float*)d_in[8];  const float* bk  = (const float*)d_in[9];
    const float* Wv  = (const float*)d_in[10]; const float* bv  = (const float*)d_in[11];
    const float* W1  = (const float*)d_in[12]; const float* b1  = (const float*)d_in[13];
    const float* W2  = (const float*)d_in[14]; const float* b2  = (const float*)d_in[15];
    const float* g1  = (const float*)d_in[16]; const float* be1 = (const float*)d_in[17];
    const float* Wf1 = (const float*)d_in[18]; const float* bf1 = (const float*)d_in[19];
    const float* Wf2 = (const float*)d_in[20]; const float* bf2 = (const float*)d_in[21];
    const float* g2  = (const float*)d_in[22]; const float* be2 = (const float*)d_in[23];

    float* ws = (float*)d_ws;
    // workspace (float units), total 7,864,320 f = 30 MB:
    // A 0..1572864:        qkvb bf16 [2048][1536]  -> yb f32 [2048][512]
    // B 1572864..2097152:  vT bf16 [512][2048]     -> h1 bf16
    // C 2097152..4194304:  xb bf16 (head) -> msgT bf16 [8][2048][256] -> g3
    // D 4194304..5242880:  biasMs bf16 [2048][1024] -> h2/fb bf16
    // E 5242880..5767168:  bqkv f32 (head) -> yb16 bf16
    // F 5767168..7864320:  persistent bf16 weights
    unsigned short* qkvb   = (unsigned short*)(ws + 0);
    float*          yb     = ws + 0;
    unsigned short* vT     = (unsigned short*)(ws + 1572864);
    unsigned short* h1     = (unsigned short*)(ws + 1572864);
    unsigned short* xb     = (unsigned short*)(ws + 2097152);
    unsigned short* msgT   = (unsigned short*)(ws + 2097152);
    unsigned short* g3     = msgT;
    unsigned short* biasMs = (unsigned short*)(ws + 4194304);
    unsigned short* h2     = (unsigned short*)(ws + 4194304);
    unsigned short* fb     = h2;
    float*          bqkv   = ws + 5242880;
    unsigned short* yb16   = (unsigned short*)(ws + 5242880);
    unsigned short* Wqkvt  = (unsigned short*)(ws + 5767168);
    unsigned short* W1t    = (unsigned short*)(ws + 6160384);
    unsigned short* W2t    = (unsigned short*)(ws + 6684672);
    unsigned short* Wf1t   = (unsigned short*)(ws + 6815744);
    unsigned short* Wf2t   = (unsigned short*)(ws + 7340032);
    float*          outp   = (float*)d_out;

    dim3 thr(256);
    const int M = BB * NN;  // 2048

    prep_kernel<<<dim3(1024, 1, 9), thr, 0, stream>>>(
        x, Wq, Wk, Wv, W1, W2, Wf1, Wf2, bq, bk, bv,
        xb, Wqkvt, W1t, W2t, Wf1t, Wf2t, bqkv);
    prep_bias<<<dim3(2048), thr, 0, stream>>>(attn_bias, mask, dist, dist_bar, biasMs);

    // fused QKV: [2048,512] @ [512,1536]; v written transposed into vT
    mfma_gemm128<0,1><<<dim3(12, 16), thr, 0, stream>>>(xb, Wqkvt, bqkv, qkvb, vT, M, 1536, DD);

    // 4-scale MFMA attention -> bf16 msgT (scrambled W1-input layout)
    attn_kernel<<<dim3(4, HH, BB), thr, 0, stream>>>(qkvb, vT, biasMs, msgT);

    // h = silu(msgT @ W1 + b1) @ W2 + b2
    mfma_gemm64<1><<<dim3(8, 32), thr, 0, stream>>>(msgT, W1t, b1, h1, M, DD, 2048);
    mfma_gemm64<0><<<dim3(8, 32), thr, 0, stream>>>(h1, W2t, b2, h2, M, DD, DD);

    // y = LN(h + x)
    ln_kernel<<<dim3(M), thr, 0, stream>>>(h2, x, g1, be1, yb, yb16);

    // f = gelu(y @ Wf1 + bf1) @ Wf2 + bf2
    mfma_gemm128<2,0><<<dim3(16, 16), thr, 0, stream>>>(yb16, Wf1t, bf1, g3, nullptr, M, FFN_, DD);
    mfma_gemm64<0><<<dim3(8, 32), thr, 0, stream>>>(g3, Wf2t, bf2, fb, M, DD, 2048);

    // out = LN(f + y)
    ln_kernel<<<dim3(M), thr, 0, stream>>>(fb, yb, g2, be2, outp, nullptr);
}

// Round 4
// 254.021 us; speedup vs baseline: 3.0429x; 1.0512x over previous
//
#include <hip/hip_runtime.h>
#include <math.h>

#define BB 8
#define NN 256
#define DD 512
#define HH 16
#define KK 4
#define DKK 32
#define FFN_ 2048
#define NEGV -1e12f

typedef __attribute__((ext_vector_type(8))) short bf16x8;
typedef __attribute__((ext_vector_type(4))) float f32x4;

__device__ __forceinline__ unsigned short f2bf(float f) {
    union { float f; unsigned int u; } v; v.f = f;
    unsigned int r = (v.u + 0x7FFFu + ((v.u >> 16) & 1u)) >> 16;
    return (unsigned short)r;
}
__device__ __forceinline__ float bf2f(unsigned short u) {
    union { unsigned int i; float f; } v; v.i = ((unsigned int)u) << 16;
    return v.f;
}
__device__ __forceinline__ void gload_lds16(const unsigned short* g, unsigned short* l) {
    __builtin_amdgcn_global_load_lds(
        (const __attribute__((address_space(1))) void*)g,
        (__attribute__((address_space(3))) void*)l, 16, 0, 0);
}

// ---------------------------------------------------------------------------
// Merged prep: z=0..6 weight transposes fp32->bf16 Wt[N][K]; z=7 x->bf16;
// z=8 bias concat; z=9 mask+bias combine (biasMs).
// ---------------------------------------------------------------------------
__global__ __launch_bounds__(256) void prep_kernel(
    const float* __restrict__ x,
    const float* __restrict__ Wq, const float* __restrict__ Wk,
    const float* __restrict__ Wv, const float* __restrict__ W1,
    const float* __restrict__ W2, const float* __restrict__ Wf1,
    const float* __restrict__ Wf2,
    const float* __restrict__ bq, const float* __restrict__ bk,
    const float* __restrict__ bv,
    const float* __restrict__ attn_bias, const int* __restrict__ mask,
    const float* __restrict__ dist, const float* __restrict__ dist_bar,
    unsigned short* __restrict__ xb, unsigned short* __restrict__ Wqkvt,
    unsigned short* __restrict__ W1t, unsigned short* __restrict__ W2t,
    unsigned short* __restrict__ Wf1t, unsigned short* __restrict__ Wf2t,
    float* __restrict__ bqkv, unsigned short* __restrict__ biasMs)
{
    const int z = blockIdx.z;
    const int t = threadIdx.x;

    if (z == 7) {  // x convert (1024 blocks)
        if (blockIdx.x >= 1024) return;
        const int i0 = blockIdx.x * 1024 + t * 4;
        float4 xv = *(const float4*)(x + i0);
        ushort4 o;
        o.x = f2bf(xv.x); o.y = f2bf(xv.y); o.z = f2bf(xv.z); o.w = f2bf(xv.w);
        *(ushort4*)(xb + i0) = o;
        return;
    }
    if (z == 8) {  // bias concat (6 blocks)
        if (blockIdx.x >= 6) return;
        const int i = blockIdx.x * 256 + t;
        float v = (i < 512) ? bq[i] : (i < 1024) ? bk[i - 512] : bv[i - 1024];
        bqkv[i] = v;
        return;
    }
    if (z == 9) {  // biasMs: (b*4+ks)*64+rg blocks, 2048 total
        const int bx = blockIdx.x;
        const int rg = bx & 63, ks = (bx >> 6) & 3, b = bx >> 8;
        const int m = t;
        const float bar = dist_bar[ks];
        ushort4 o;
        unsigned short* po = (unsigned short*)&o;
        #pragma unroll
        for (int i = 0; i < 4; ++i) {
            const int n = rg * 4 + i;
            const int mk = mask[((size_t)(b * NN) + n) * NN + m];
            bool allowed = (n == 0) || (m == 0);
            if (!allowed)
                allowed = dist[((size_t)(b * 255) + (n - 1)) * 255 + (m - 1)] < bar;
            const float bias = attn_bias[(((size_t)(b * KK) + ks) * NN + n) * NN + m];
            po[i] = f2bf((mk != 0 && allowed) ? bias : NEGV);
        }
        *(ushort4*)(biasMs + (size_t)bx * 1024 + m * 4) = o;
        return;
    }

    const float* src; unsigned short* dst; int Kd, Nd;
    switch (z) {
        case 0: src = Wq;  dst = Wqkvt;              Kd = 512;  Nd = 512;  break;
        case 1: src = Wk;  dst = Wqkvt + 512 * 512;  Kd = 512;  Nd = 512;  break;
        case 2: src = Wv;  dst = Wqkvt + 1024 * 512; Kd = 512;  Nd = 512;  break;
        case 3: src = W1;  dst = W1t;  Kd = 2048; Nd = 512;  break;
        case 4: src = W2;  dst = W2t;  Kd = 512;  Nd = 512;  break;
        case 5: src = Wf1; dst = Wf1t; Kd = 512;  Nd = 2048; break;
        default: src = Wf2; dst = Wf2t; Kd = 2048; Nd = 512; break;
    }
    const int ktiles = Kd / 32, ntiles = Nd / 32;
    const int ti = blockIdx.x;
    if (ti >= ktiles * ntiles) return;
    const int k0 = (ti % ktiles) * 32, n0 = (ti / ktiles) * 32;

    __shared__ float tile[32][33];
    const int xx = t & 31, yy = t >> 5;
    #pragma unroll
    for (int r = 0; r < 4; ++r)
        tile[yy * 4 + r][xx] = src[(size_t)(k0 + yy * 4 + r) * Nd + n0 + xx];
    __syncthreads();
    #pragma unroll
    for (int r = 0; r < 4; ++r)
        dst[(size_t)(n0 + yy * 4 + r) * Kd + k0 + xx] = f2bf(tile[xx][yy * 4 + r]);
}

// ---------------------------------------------------------------------------
// 512-thread 128x128 MFMA GEMM, 8 waves (4m x 2n), BK=64, optional split-K.
// EPI 0: bf16 out + ACT.  EPI 1: QKV split (col<1024 -> Cb pitch 1536, else
// vT transposed).  EPI 2: fp32 partials Cp + z*M*N (no bias/act).
// ---------------------------------------------------------------------------
template<int ACT, int EPI, int KSPLIT>
__global__ __launch_bounds__(512) void mfma_gemm512(
    const unsigned short* __restrict__ A, const unsigned short* __restrict__ Bt,
    const float* __restrict__ bias, unsigned short* __restrict__ Cb,
    unsigned short* __restrict__ vT, float* __restrict__ Cp,
    int M, int N, int Kdim)
{
    __shared__ unsigned short As[128 * 64];
    __shared__ unsigned short Bs[128 * 64];

    const int t = threadIdx.x, lane = t & 63, wv = t >> 6;
    const int n0 = blockIdx.x * 128, m0 = blockIdx.y * 128;
    const int wm = wv >> 1, wn = wv & 1;          // 4 x 2 wave grid
    const int L = lane & 15, qd = lane >> 4;
    const int sr = lane >> 3, sc = lane & 7;

    const int ksub = Kdim / KSPLIT;
    const int kbeg = blockIdx.z * ksub;

    f32x4 acc[2][4];
    #pragma unroll
    for (int i = 0; i < 2; ++i)
        #pragma unroll
        for (int j = 0; j < 4; ++j) acc[i][j] = (f32x4){0.f, 0.f, 0.f, 0.f};

    for (int kt = kbeg; kt < kbeg + ksub; kt += 64) {
        #pragma unroll
        for (int p = 0; p < 2; ++p) {
            const int rbase = wv * 16 + p * 8;
            gload_lds16(A  + (size_t)(m0 + rbase + sr) * Kdim + kt + sc * 8,
                        As + rbase * 64);
            gload_lds16(Bt + (size_t)(n0 + rbase + sr) * Kdim + kt + sc * 8,
                        Bs + rbase * 64);
        }
        __syncthreads();
        #pragma unroll
        for (int s = 0; s < 2; ++s) {
            bf16x8 af[2], bfb[4];
            #pragma unroll
            for (int i = 0; i < 2; ++i)
                af[i] = *(const bf16x8*)(As + (wm * 32 + i * 16 + L) * 64 + s * 32 + qd * 8);
            #pragma unroll
            for (int j = 0; j < 4; ++j)
                bfb[j] = *(const bf16x8*)(Bs + (wn * 64 + j * 16 + L) * 64 + s * 32 + qd * 8);
            #pragma unroll
            for (int i = 0; i < 2; ++i)
                #pragma unroll
                for (int j = 0; j < 4; ++j)
                    acc[i][j] = __builtin_amdgcn_mfma_f32_16x16x32_bf16(af[i], bfb[j], acc[i][j], 0, 0, 0);
        }
        __syncthreads();
    }

    #pragma unroll
    for (int j = 0; j < 4; ++j) {
        const int col = n0 + wn * 64 + j * 16 + L;
        #pragma unroll
        for (int i = 0; i < 2; ++i) {
            const int rowb = m0 + wm * 32 + i * 16 + qd * 4;
            if (EPI == 2) {
                float* cp = Cp + (size_t)blockIdx.z * M * N + (size_t)rowb * N + col;
                #pragma unroll
                for (int r = 0; r < 4; ++r) cp[(size_t)r * N] = acc[i][j][r];
            } else if (EPI == 1 && col >= 1024) {
                const float bv = bias[col];
                ushort4 pk;
                unsigned short* pp = (unsigned short*)&pk;
                #pragma unroll
                for (int r = 0; r < 4; ++r) pp[r] = f2bf(acc[i][j][r] + bv);
                *(ushort4*)(vT + (size_t)(col - 1024) * 2048 + rowb) = pk;
            } else {
                const float bv = bias[col];
                #pragma unroll
                for (int r = 0; r < 4; ++r) {
                    float v = acc[i][j][r] + bv;
                    if (ACT == 1) v = v / (1.0f + __expf(-v));
                    else if (ACT == 2) v = 0.5f * v * (1.0f + erff(v * 0.70710678118654752f));
                    Cb[(size_t)(rowb + r) * N + col] = f2bf(v);
                }
            }
        }
    }
}

// ---------------------------------------------------------------------------
// Finalize split-K: h1 = silu(sum_z Cp[z] + b1) -> bf16.  N=512, block/row.
// ---------------------------------------------------------------------------
__global__ __launch_bounds__(256) void fin_silu(
    const float* __restrict__ Cp, const float* __restrict__ bias,
    unsigned short* __restrict__ out)
{
    const int row = blockIdx.x, t = threadIdx.x;
    const int c0 = t * 2;
    const size_t base = (size_t)row * DD;
    float sx = 0.f, sy = 0.f;
    #pragma unroll
    for (int z = 0; z < 4; ++z) {
        const float2 p = *(const float2*)(Cp + (size_t)z * (2048u * 512u) + base + c0);
        sx += p.x; sy += p.y;
    }
    float v0 = sx + bias[c0], v1 = sy + bias[c0 + 1];
    v0 = v0 / (1.0f + __expf(-v0));
    v1 = v1 / (1.0f + __expf(-v1));
    ushort2 pk; pk.x = f2bf(v0); pk.y = f2bf(v1);
    *(ushort2*)(out + base + c0) = pk;
}

// ---------------------------------------------------------------------------
// Finalize split-K + residual + LayerNorm.  z = sum_z Cp[z] + bias + res;
// out = LN(z)*g + be (f32, optional bf16 copy).  N=512, block per row.
// ---------------------------------------------------------------------------
template<int KS, int OUT16>
__global__ __launch_bounds__(256) void fin_ln(
    const float* __restrict__ Cp, const float* __restrict__ bias,
    const float* __restrict__ res, const float* __restrict__ g,
    const float* __restrict__ be, float* __restrict__ out,
    unsigned short* __restrict__ outb)
{
    const int row = blockIdx.x, t = threadIdx.x;
    const int c0 = t * 2;
    const size_t base = (size_t)row * DD;
    __shared__ float red[256];

    float sx = 0.f, sy = 0.f;
    #pragma unroll
    for (int z = 0; z < KS; ++z) {
        const float2 p = *(const float2*)(Cp + (size_t)z * (2048u * 512u) + base + c0);
        sx += p.x; sy += p.y;
    }
    const float2 rv = *(const float2*)(res + base + c0);
    const float z0 = sx + bias[c0]     + rv.x;
    const float z1 = sy + bias[c0 + 1] + rv.y;

    red[t] = z0 + z1; __syncthreads();
    for (int s = 128; s > 0; s >>= 1) {
        if (t < s) red[t] += red[t + s];
        __syncthreads();
    }
    const float mean = red[0] * (1.0f / 512.0f); __syncthreads();

    const float d0 = z0 - mean, d1 = z1 - mean;
    red[t] = d0 * d0 + d1 * d1; __syncthreads();
    for (int s = 128; s > 0; s >>= 1) {
        if (t < s) red[t] += red[t + s];
        __syncthreads();
    }
    const float inv = rsqrtf(red[0] * (1.0f / 512.0f) + 1e-6f);

    const float o0 = d0 * inv * g[c0]     + be[c0];
    const float o1 = d1 * inv * g[c0 + 1] + be[c0 + 1];
    out[base + c0]     = o0;
    out[base + c0 + 1] = o1;
    if (OUT16) {
        ushort2 pk; pk.x = f2bf(o0); pk.y = f2bf(o1);
        *(ushort2*)(outb + base + c0) = pk;
    }
}

// ---------------------------------------------------------------------------
// MFMA attention (R3-verified): one block per (b, h, 64-query tile).
// ---------------------------------------------------------------------------
__global__ __launch_bounds__(256) void attn_kernel(
    const unsigned short* __restrict__ qkvb, const unsigned short* __restrict__ vT,
    const unsigned short* __restrict__ biasMs, unsigned short* __restrict__ msgT)
{
    const int qt = blockIdx.x, h = blockIdx.y, b = blockIdx.z;
    const int q0 = qt * 64;
    const int t = threadIdx.x, lane = t & 63, wv = t >> 6;
    const int L = lane & 15, qd = lane >> 4;

    __shared__ unsigned short Qs[64 * 32];
    __shared__ unsigned short Ks[256 * 32];
    __shared__ unsigned short Vs[32 * 264];
    __shared__ unsigned short Ps[64 * 264];
    __shared__ unsigned short Ot[32 * 72];

    {
        const int r = lane >> 2, c = lane & 3;
        gload_lds16(qkvb + (size_t)(b * NN + q0 + wv * 16 + r) * 1536 + h * DKK + c * 8,
                    Qs + wv * 16 * 32);
        #pragma unroll
        for (int p = 0; p < 4; ++p)
            gload_lds16(qkvb + (size_t)(b * NN + p * 64 + wv * 16 + r) * 1536 + 512 + h * DKK + c * 8,
                        Ks + (p * 64 + wv * 16) * 32);
    }
    {
        const int vr = t >> 3, seg = t & 7;
        const unsigned short* gv = vT + (size_t)(h * DKK + vr) * 2048 + b * NN + seg * 32;
        #pragma unroll
        for (int i = 0; i < 4; ++i) {
            bf16x8 vv = *(const bf16x8*)(gv + i * 8);
            *(bf16x8*)(Vs + vr * 264 + seg * 32 + i * 8) = vv;
        }
    }
    __syncthreads();

    f32x4 S[16];
    #pragma unroll
    for (int j = 0; j < 16; ++j) S[j] = (f32x4){0.f, 0.f, 0.f, 0.f};
    {
        const bf16x8 aq = *(const bf16x8*)(Qs + (wv * 16 + L) * 32 + qd * 8);
        #pragma unroll
        for (int j = 0; j < 16; ++j) {
            const bf16x8 bk = *(const bf16x8*)(Ks + (j * 16 + L) * 32 + qd * 8);
            S[j] = __builtin_amdgcn_mfma_f32_16x16x32_bf16(aq, bk, S[j], 0, 0, 0);
        }
    }
    const float scale = 0.17677669529663687f;
    const int rgb = (q0 + wv * 16) >> 2;

    for (int ks = 0; ks < KK; ++ks) {
        const unsigned short* bp = biasMs + ((size_t)((b * KK + ks) * 64 + rgb + qd)) * 1024;

        ushort4 b4[16];
        float mx[4] = {-3e38f, -3e38f, -3e38f, -3e38f};
        #pragma unroll
        for (int j = 0; j < 16; ++j) {
            b4[j] = *(const ushort4*)(bp + (j * 16 + L) * 4);
            const unsigned short* pb = (const unsigned short*)&b4[j];
            #pragma unroll
            for (int r = 0; r < 4; ++r)
                mx[r] = fmaxf(mx[r], S[j][r] * scale + bf2f(pb[r]));
        }
        #pragma unroll
        for (int off = 8; off > 0; off >>= 1)
            #pragma unroll
            for (int r = 0; r < 4; ++r)
                mx[r] = fmaxf(mx[r], __shfl_xor(mx[r], off));

        float sm[4] = {0.f, 0.f, 0.f, 0.f};
        #pragma unroll
        for (int j = 0; j < 16; ++j) {
            const unsigned short* pb = (const unsigned short*)&b4[j];
            #pragma unroll
            for (int r = 0; r < 4; ++r) {
                const float e = __expf(S[j][r] * scale + bf2f(pb[r]) - mx[r]);
                sm[r] += e;
                Ps[(wv * 16 + qd * 4 + r) * 264 + j * 16 + L] = f2bf(e);
            }
        }
        #pragma unroll
        for (int off = 8; off > 0; off >>= 1)
            #pragma unroll
            for (int r = 0; r < 4; ++r)
                sm[r] += __shfl_xor(sm[r], off);
        float inv[4];
        #pragma unroll
        for (int r = 0; r < 4; ++r) inv[r] = 1.0f / sm[r];

        f32x4 O[2];
        O[0] = (f32x4){0.f, 0.f, 0.f, 0.f};
        O[1] = (f32x4){0.f, 0.f, 0.f, 0.f};
        #pragma unroll
        for (int kc = 0; kc < 8; ++kc) {
            const bf16x8 ap = *(const bf16x8*)(Ps + (wv * 16 + L) * 264 + kc * 32 + qd * 8);
            #pragma unroll
            for (int jt = 0; jt < 2; ++jt) {
                const bf16x8 bv = *(const bf16x8*)(Vs + (jt * 16 + L) * 264 + kc * 32 + qd * 8);
                O[jt] = __builtin_amdgcn_mfma_f32_16x16x32_bf16(ap, bv, O[jt], 0, 0, 0);
            }
        }
        #pragma unroll
        for (int jt = 0; jt < 2; ++jt)
            #pragma unroll
            for (int r = 0; r < 4; ++r)
                Ot[(jt * 16 + L) * 72 + wv * 16 + qd * 4 + r] = f2bf(O[jt][r] * inv[r]);
        __syncthreads();

        {
            const int dd = t >> 3, cc = t & 7;
            bf16x8 ov = *(const bf16x8*)(Ot + dd * 72 + cc * 8);
            *(bf16x8*)(msgT + (size_t)b * 524288 +
                       ((size_t)((ks * HH + h) * DKK + dd)) * NN + q0 + cc * 8) = ov;
        }
        __syncthreads();
    }
}

// ---------------------------------------------------------------------------
extern "C" void kernel_launch(void* const* d_in, const int* in_sizes, int n_in,
                              void* d_out, int out_size, void* d_ws, size_t ws_size,
                              hipStream_t stream)
{
    const float* x         = (const float*)d_in[0];
    const float* dist      = (const float*)d_in[1];
    const float* dist_bar  = (const float*)d_in[2];
    const float* attn_bias = (const float*)d_in[3];
    const int*   mask      = (const int*)d_in[4];
    const float* Wq  = (const float*)d_in[6];  const float* bq  = (const float*)d_in[7];
    const float* Wk  = (const float*)d_in[8];  const float* bk  = (const float*)d_in[9];
    const float* Wv  = (const float*)d_in[10]; const float* bv  = (const float*)d_in[11];
    const float* W1  = (const float*)d_in[12]; const float* b1  = (const float*)d_in[13];
    const float* W2  = (const float*)d_in[14]; const float* b2  = (const float*)d_in[15];
    const float* g1  = (const float*)d_in[16]; const float* be1 = (const float*)d_in[17];
    const float* Wf1 = (const float*)d_in[18]; const float* bf1 = (const float*)d_in[19];
    const float* Wf2 = (const float*)d_in[20]; const float* bf2 = (const float*)d_in[21];
    const float* g2  = (const float*)d_in[22]; const float* be2 = (const float*)d_in[23];

    float* ws = (float*)d_ws;
    // workspace layout (float units), no time-overlapping reuse except msgT/g3:
    unsigned short* qkvb   = (unsigned short*)(ws + 0);          // bf16 [2048][1536]
    unsigned short* vT     = (unsigned short*)(ws + 1572864);    // bf16 [512][2048]
    unsigned short* xb     = (unsigned short*)(ws + 2097152);    // bf16 [2048][512]
    unsigned short* msgT   = (unsigned short*)(ws + 2621440);    // bf16 [8][2048][256] / g3 [2048][2048]
    unsigned short* g3     = msgT;
    unsigned short* biasMs = (unsigned short*)(ws + 4718592);    // bf16 [2048][1024]
    float*          bqkv   = ws + 5767168;                       // f32 [1536]
    unsigned short* h1     = (unsigned short*)(ws + 5771264);    // bf16 [2048][512]
    float*          yb     = ws + 6295552;                       // f32 [2048][512]
    unsigned short* yb16   = (unsigned short*)(ws + 7344128);    // bf16 [2048][512]
    unsigned short* Wqkvt  = (unsigned short*)(ws + 7868416);    // bf16 [1536][512]
    unsigned short* W1t    = (unsigned short*)(ws + 8261632);    // bf16 [512][2048]
    unsigned short* W2t    = (unsigned short*)(ws + 8785920);    // bf16 [512][512]
    unsigned short* Wf1t   = (unsigned short*)(ws + 8916992);    // bf16 [2048][512]
    unsigned short* Wf2t   = (unsigned short*)(ws + 9441280);    // bf16 [512][2048]
    float*          part   = ws + 9965568;                       // f32 [4][2048][512]
    float*          outp   = (float*)d_out;

    const int M = BB * NN;  // 2048

    // 1 prep launch: weights, x, bqkv, biasMs
    prep_kernel<<<dim3(2048, 1, 10), dim3(256), 0, stream>>>(
        x, Wq, Wk, Wv, W1, W2, Wf1, Wf2, bq, bk, bv,
        attn_bias, mask, dist, dist_bar,
        xb, Wqkvt, W1t, W2t, Wf1t, Wf2t, bqkv, biasMs);

    // fused QKV: [2048,512] @ [512,1536]; v written transposed into vT
    mfma_gemm512<0,1,1><<<dim3(12, 16, 1), dim3(512), 0, stream>>>(
        xb, Wqkvt, bqkv, qkvb, vT, nullptr, M, 1536, DD);

    // 4-scale MFMA attention -> bf16 msgT
    attn_kernel<<<dim3(4, HH, BB), dim3(256), 0, stream>>>(qkvb, vT, biasMs, msgT);

    // h1 = silu(msgT @ W1 + b1): split-K=4 -> partials -> finalize
    mfma_gemm512<0,2,4><<<dim3(4, 16, 4), dim3(512), 0, stream>>>(
        msgT, W1t, nullptr, nullptr, nullptr, part, M, DD, 2048);
    fin_silu<<<dim3(M), dim3(256), 0, stream>>>(part, b1, h1);

    // h2 = h1 @ W2 + b2 (split-K=2), then y = LN(h2 + x) fused in finalize
    mfma_gemm512<0,2,2><<<dim3(4, 16, 2), dim3(512), 0, stream>>>(
        h1, W2t, nullptr, nullptr, nullptr, part, M, DD, DD);
    fin_ln<2,1><<<dim3(M), dim3(256), 0, stream>>>(part, b2, x, g1, be1, yb, yb16);

    // g3 = gelu(y @ Wf1 + bf1)
    mfma_gemm512<2,0,1><<<dim3(16, 16, 1), dim3(512), 0, stream>>>(
        yb16, Wf1t, bf1, g3, nullptr, nullptr, M, FFN_, DD);

    // f = g3 @ Wf2 + bf2 (split-K=4), then out = LN(f + y) fused in finalize
    mfma_gemm512<0,2,4><<<dim3(4, 16, 4), dim3(512), 0, stream>>>(
        g3, Wf2t, nullptr, nullptr, nullptr, part, M, DD, 2048);
    fin_ln<4,0><<<dim3(M), dim3(256), 0, stream>>>(part, bf2, yb, g2, be2, outp, nullptr);
}